// Round 1
// baseline (221.568 us; speedup 1.0000x reference)
//
#include <hip/hip_runtime.h>

// CrossAttention with LoRA (folded): B=16, C=64, H=W=64 (hw=4096), L=77, COND=768,
// HEADS=8, dh=8, R=8, SCALING=1, SCALE=8^-0.5.
//
// Pipeline:
//   1. prep_weights: W_eff^T = (W + B@A)^T  stored [in][out], for q,k,v,o
//   2. proj64 (q):   qT[b][c][p] = (z_flat @ Wq_eff^T + bq) * SCALE*log2e   (qT lives in d_out as scratch)
//   3. kvproj:       split-K partials for k,v  (12 chunks of 64 over COND=768)
//   4. kvreduce:     k[b][l][c], v[b][l][c] = sum(partials) + bias
//   5. attn:         single-pass softmax (logits bounded => no max-sub), exp2, k/v in LDS
//   6. proj64 (o):   out[b][c][p] = aoT @ Wo_eff^T + bo   (final [B,C,H,W] layout directly)

#define HW   4096
#define CHN  64
#define LSEQ 77
#define CD   768
#define NB   16

// workspace float offsets
#define OFF_WQ 0
#define OFF_WK 4096
#define OFF_WV 53248
#define OFF_WO 102400
#define OFF_K  106496
#define OFF_V  185344
#define OFF_PA 264192   // partials [2][12][16][77*64] = 1,892,352 floats
#define OFF_AO 264192   // aoT [16][64][4096] aliases partials (dead by then)

__global__ __launch_bounds__(256) void prep_weights(
    const float* __restrict__ Wq, const float* __restrict__ Aq, const float* __restrict__ Bq,
    const float* __restrict__ Wk, const float* __restrict__ Ak, const float* __restrict__ Bk,
    const float* __restrict__ Wv, const float* __restrict__ Av, const float* __restrict__ Bv,
    const float* __restrict__ Wo, const float* __restrict__ Ao, const float* __restrict__ Bo,
    float* __restrict__ ws) {
  int idx = blockIdx.x * 256 + threadIdx.x;   // 416*256 = 106496 exact
  const float *W, *A, *Bm;
  float* out;
  int in_d, local;
  if (idx < 4096)        { W = Wq; A = Aq; Bm = Bq; out = ws + OFF_WQ; in_d = 64;  local = idx; }
  else if (idx < 53248)  { W = Wk; A = Ak; Bm = Bk; out = ws + OFF_WK; in_d = 768; local = idx - 4096; }
  else if (idx < 102400) { W = Wv; A = Av; Bm = Bv; out = ws + OFF_WV; in_d = 768; local = idx - 53248; }
  else                   { W = Wo; A = Ao; Bm = Bo; out = ws + OFF_WO; in_d = 64;  local = idx - 102400; }
  int co = local & 63;
  int c  = local >> 6;
  float val = W[co * in_d + c];
  #pragma unroll
  for (int r = 0; r < 8; r++) val += Bm[co * 8 + r] * A[r * in_d + c];
  out[local] = val;   // local == c*64+co : W_eff^T [in][out]
}

// y[b][co][p] = (sum_c x[b][c][p] * wT[c][co] + bias[co]) * scale
// One thread per p. x-row in VGPRs; wT/bias indices wave-uniform -> scalar loads via K$.
__global__ __launch_bounds__(256, 1) void proj64(
    const float* __restrict__ x,     // [16][64][4096]
    const float* __restrict__ wT,    // [64][64] = [c][co]
    const float* __restrict__ bias,  // [64]
    float* __restrict__ y,           // [16][64][4096]
    float scale) {
  int b = blockIdx.y;
  int p = blockIdx.x * 256 + threadIdx.x;
  const float* xb = x + b * (CHN * HW) + p;
  float zr[64];
  #pragma unroll
  for (int c = 0; c < 64; c++) zr[c] = xb[c * HW];
  float acc[64];
  #pragma unroll
  for (int co = 0; co < 64; co++) acc[co] = bias[co];
  #pragma unroll 4
  for (int c = 0; c < 64; c++) {
    float zv = zr[c];
    #pragma unroll
    for (int co = 0; co < 64; co++) acc[co] = fmaf(zv, wT[c * 64 + co], acc[co]);
  }
  float* yb = y + b * (CHN * HW) + p;
  #pragma unroll
  for (int co = 0; co < 64; co++) yb[co * HW] = acc[co] * scale;
}

// split-K partial projection of cond -> k/v. grid (12 kchunks, 2 kv, 16 b), block 128 (lane = l).
__global__ __launch_bounds__(128, 1) void kvproj(
    const float* __restrict__ cond,  // [16][77][768]
    const float* __restrict__ wkT,   // [768][64]
    const float* __restrict__ wvT,
    float* __restrict__ part) {      // [2][12][16][77*64]
  int chunk = blockIdx.x;
  int kv    = blockIdx.y;
  int b     = blockIdx.z;
  int l     = threadIdx.x;
  if (l >= LSEQ) return;
  const float* wT = kv ? wvT : wkT;
  int c0 = chunk * 64;
  const float* xr = cond + (b * LSEQ + l) * CD + c0;
  float zr[64];
  #pragma unroll
  for (int i = 0; i < 16; i++) {
    float4 t4 = ((const float4*)xr)[i];
    zr[4*i] = t4.x; zr[4*i+1] = t4.y; zr[4*i+2] = t4.z; zr[4*i+3] = t4.w;
  }
  float acc[64];
  #pragma unroll
  for (int co = 0; co < 64; co++) acc[co] = 0.f;
  #pragma unroll 4
  for (int c = 0; c < 64; c++) {
    float zv = zr[c];
    #pragma unroll
    for (int co = 0; co < 64; co++) acc[co] = fmaf(zv, wT[(c0 + c) * 64 + co], acc[co]);
  }
  float* pout = part + (((kv * 12 + chunk) * NB + b) * LSEQ + l) * 64;
  #pragma unroll
  for (int i = 0; i < 16; i++) {
    ((float4*)pout)[i] = make_float4(acc[4*i], acc[4*i+1], acc[4*i+2], acc[4*i+3]);
  }
}

__global__ __launch_bounds__(256) void kvreduce(
    const float* __restrict__ part,
    const float* __restrict__ bk, const float* __restrict__ bv,
    float* __restrict__ kbuf, float* __restrict__ vbuf) {
  int idx = blockIdx.x * 256 + threadIdx.x;  // 616*256 = 157696 exact
  int kv = idx / (NB * LSEQ * 64);
  int r  = idx - kv * (NB * LSEQ * 64);
  int co = idx & 63;
  float val = kv ? bv[co] : bk[co];
  #pragma unroll
  for (int ch = 0; ch < 12; ch++)
    val += part[(kv * 12 + ch) * (NB * LSEQ * 64) + r];
  (kv ? vbuf : kbuf)[r] = val;
}

// grid (16 ptiles, 16 b), block 256: h = t>>5 (8 heads), pl = t&31; 8 pixels/thread.
// q is pre-scaled by SCALE*log2e; logits bounded (|s| < ~1) => exp2 without max-subtraction.
__global__ __launch_bounds__(256, 1) void attn(
    const float* __restrict__ qT,    // [16][64][4096]
    const float* __restrict__ kbuf,  // [16][77][64]
    const float* __restrict__ vbuf,
    float* __restrict__ aoT) {       // [16][64][4096]
  __shared__ float4 ks4[LSEQ * 16];
  __shared__ float4 vs4[LSEQ * 16];
  int b  = blockIdx.y;
  int p0 = blockIdx.x * 256;
  int t  = threadIdx.x;
  const float4* ksrc = (const float4*)(kbuf + b * LSEQ * 64);
  const float4* vsrc = (const float4*)(vbuf + b * LSEQ * 64);
  for (int i = t; i < LSEQ * 16; i += 256) { ks4[i] = ksrc[i]; vs4[i] = vsrc[i]; }
  __syncthreads();
  const float* ks = (const float*)ks4;
  const float* vs = (const float*)vs4;
  int h  = t >> 5;
  int pl = t & 31;
  const float* qb = qT + b * (CHN * HW) + (h * 8) * HW + p0 + pl;
  float qr[8][8];
  #pragma unroll
  for (int i = 0; i < 8; i++)
    #pragma unroll
    for (int d = 0; d < 8; d++) qr[i][d] = qb[d * HW + 32 * i];
  float acc[8][8];
  float li[8];
  #pragma unroll
  for (int i = 0; i < 8; i++) {
    li[i] = 0.f;
    #pragma unroll
    for (int d = 0; d < 8; d++) acc[i][d] = 0.f;
  }
  for (int j = 0; j < LSEQ; j++) {
    float kf[8], vf[8];
    #pragma unroll
    for (int d = 0; d < 8; d++) kf[d] = ks[j * 64 + h * 8 + d];
    #pragma unroll
    for (int d = 0; d < 8; d++) vf[d] = vs[j * 64 + h * 8 + d];
    #pragma unroll
    for (int i = 0; i < 8; i++) {
      float s = qr[i][0] * kf[0];
      #pragma unroll
      for (int d = 1; d < 8; d++) s = fmaf(qr[i][d], kf[d], s);
      float e = __builtin_amdgcn_exp2f(s);
      li[i] += e;
      #pragma unroll
      for (int d = 0; d < 8; d++) acc[i][d] = fmaf(e, vf[d], acc[i][d]);
    }
  }
  float* ob = aoT + b * (CHN * HW) + (h * 8) * HW + p0 + pl;
  #pragma unroll
  for (int i = 0; i < 8; i++) {
    float inv = 1.0f / li[i];
    #pragma unroll
    for (int d = 0; d < 8; d++) ob[d * HW + 32 * i] = acc[i][d] * inv;
  }
}

extern "C" void kernel_launch(void* const* d_in, const int* in_sizes, int n_in,
                              void* d_out, int out_size, void* d_ws, size_t ws_size,
                              hipStream_t stream) {
  const float* z    = (const float*)d_in[0];
  const float* cond = (const float*)d_in[1];
  const float* Wq = (const float*)d_in[2];  const float* bq = (const float*)d_in[3];
  const float* Aq = (const float*)d_in[4];  const float* Bq = (const float*)d_in[5];
  const float* Wk = (const float*)d_in[6];  const float* bk = (const float*)d_in[7];
  const float* Ak = (const float*)d_in[8];  const float* Bk = (const float*)d_in[9];
  const float* Wv = (const float*)d_in[10]; const float* bv = (const float*)d_in[11];
  const float* Av = (const float*)d_in[12]; const float* Bv = (const float*)d_in[13];
  const float* Wo = (const float*)d_in[14]; const float* bo = (const float*)d_in[15];
  const float* Ao = (const float*)d_in[16]; const float* Bo = (const float*)d_in[17];
  float* ws  = (float*)d_ws;
  float* out = (float*)d_out;

  // qT uses d_out as scratch (dead before the final proj64 writes out)
  float* qT = out;

  prep_weights<<<416, 256, 0, stream>>>(Wq, Aq, Bq, Wk, Ak, Bk, Wv, Av, Bv, Wo, Ao, Bo, ws);

  const float QF = 0.35355339059327373f * 1.4426950408889634f;  // SCALE * log2(e)
  proj64<<<dim3(16, 16), 256, 0, stream>>>(z, ws + OFF_WQ, bq, qT, QF);

  kvproj<<<dim3(12, 2, 16), 128, 0, stream>>>(cond, ws + OFF_WK, ws + OFF_WV, ws + OFF_PA);
  kvreduce<<<616, 256, 0, stream>>>(ws + OFF_PA, bk, bv, ws + OFF_K, ws + OFF_V);

  attn<<<dim3(16, 16), 256, 0, stream>>>(qT, ws + OFF_K, ws + OFF_V, ws + OFF_AO);

  proj64<<<dim3(16, 16), 256, 0, stream>>>(ws + OFF_AO, ws + OFF_WO, bo, out, 1.0f);
}

// Round 2
// 178.409 us; speedup vs baseline: 1.2419x; 1.2419x over previous
//
#include <hip/hip_runtime.h>

// CrossAttention with LoRA (folded). B=16, C=64, hw=4096, L=77, COND=768, HEADS=8, dh=8.
// Round 2: fused megattn = q-proj + attention + o-proj in one kernel (512 blocks, 2/CU).
// Pipeline: prep_weights -> kvproj (split-K) -> kvreduce -> megattn.

#define HW   4096
#define CHN  64
#define LSEQ 77
#define CD   768
#define NB   16

// workspace float offsets
#define OFF_WQ 0
#define OFF_WK 4096
#define OFF_WV 53248
#define OFF_WO 102400
#define OFF_K  106496
#define OFF_V  185344
#define OFF_PA 264192   // partials [2][12][16][77*64]

#define QF 0.51011784563163f  // SCALE * log2(e) = 8^-0.5 * 1.442695...

__global__ __launch_bounds__(256) void prep_weights(
    const float* __restrict__ Wq, const float* __restrict__ Aq, const float* __restrict__ Bq,
    const float* __restrict__ Wk, const float* __restrict__ Ak, const float* __restrict__ Bk,
    const float* __restrict__ Wv, const float* __restrict__ Av, const float* __restrict__ Bv,
    const float* __restrict__ Wo, const float* __restrict__ Ao, const float* __restrict__ Bo,
    float* __restrict__ ws) {
  int idx = blockIdx.x * 256 + threadIdx.x;   // 416*256 = 106496 exact
  const float *W, *A, *Bm;
  float* out;
  int in_d, local;
  float scale = 1.0f;
  if (idx < 4096)        { W = Wq; A = Aq; Bm = Bq; out = ws + OFF_WQ; in_d = 64;  local = idx; scale = QF; }
  else if (idx < 53248)  { W = Wk; A = Ak; Bm = Bk; out = ws + OFF_WK; in_d = 768; local = idx - 4096; }
  else if (idx < 102400) { W = Wv; A = Av; Bm = Bv; out = ws + OFF_WV; in_d = 768; local = idx - 53248; }
  else                   { W = Wo; A = Ao; Bm = Bo; out = ws + OFF_WO; in_d = 64;  local = idx - 102400; }
  int co = local & 63;
  int c  = local >> 6;
  float val = W[co * in_d + c];
  #pragma unroll
  for (int r = 0; r < 8; r++) val += Bm[co * 8 + r] * A[r * in_d + c];
  out[local] = val * scale;   // local == c*64+co : W_eff^T [in][out]
}

// split-K partial projection of cond -> k/v. grid (12 kchunks, 2 kv, 16 b), block 128 (lane = l).
__global__ __launch_bounds__(128, 2) void kvproj(
    const float* __restrict__ cond,  // [16][77][768]
    const float* __restrict__ wkT,   // [768][64]
    const float* __restrict__ wvT,
    float* __restrict__ part) {      // [2][12][16][77*64]
  int chunk = blockIdx.x;
  int kv    = blockIdx.y;
  int b     = blockIdx.z;
  int l     = threadIdx.x;
  if (l >= LSEQ) return;
  const float* wT = kv ? wvT : wkT;
  int c0 = chunk * 64;
  const float* xr = cond + (b * LSEQ + l) * CD + c0;
  float zr[64];
  #pragma unroll
  for (int i = 0; i < 16; i++) {
    float4 t4 = ((const float4*)xr)[i];
    zr[4*i] = t4.x; zr[4*i+1] = t4.y; zr[4*i+2] = t4.z; zr[4*i+3] = t4.w;
  }
  float acc[64];
  #pragma unroll
  for (int co = 0; co < 64; co++) acc[co] = 0.f;
  #pragma unroll 4
  for (int c = 0; c < 64; c++) {
    float zv = zr[c];
    #pragma unroll
    for (int co = 0; co < 64; co++) acc[co] = fmaf(zv, wT[(c0 + c) * 64 + co], acc[co]);
  }
  float* pout = part + (((kv * 12 + chunk) * NB + b) * LSEQ + l) * 64;
  #pragma unroll
  for (int i = 0; i < 16; i++) {
    ((float4*)pout)[i] = make_float4(acc[4*i], acc[4*i+1], acc[4*i+2], acc[4*i+3]);
  }
}

__global__ __launch_bounds__(256) void kvreduce(
    const float* __restrict__ part,
    const float* __restrict__ bk, const float* __restrict__ bv,
    float* __restrict__ kbuf, float* __restrict__ vbuf) {
  int idx = blockIdx.x * 256 + threadIdx.x;  // 616*256 = 157696 exact
  int kv = idx / (NB * LSEQ * 64);
  int r  = idx - kv * (NB * LSEQ * 64);
  int co = idx & 63;
  float val = kv ? bv[co] : bk[co];
  #pragma unroll
  for (int ch = 0; ch < 12; ch++)
    val += part[(kv * 12 + ch) * (NB * LSEQ * 64) + r];
  (kv ? vbuf : kbuf)[r] = val;
}

// Fused q-proj + attention + o-proj.
// grid (32 ptiles of 128, 16 b), block 256. h = t>>5, pl = t&31, 4 pixels/thread.
// qT never materialized; ao round-trips through LDS (stride-65 padding, 2-way conflict = free).
// Logits bounded => single-pass softmax with exp2 (wqT pre-scaled by SCALE*log2e).
__global__ __launch_bounds__(256, 2) void megattn(
    const float* __restrict__ z,     // [16][64][4096]
    const float* __restrict__ wqT,   // [64][64] (pre-scaled by QF)
    const float* __restrict__ bq,
    const float* __restrict__ kbuf,  // [16][77][64]
    const float* __restrict__ vbuf,
    const float* __restrict__ woT,   // [64][64]
    const float* __restrict__ bo,
    float* __restrict__ out) {       // [16][64][4096]
  __shared__ float smem[LSEQ * 64 * 2];   // 9856 floats: k|v ; later reused as ao[128][65]
  int b  = blockIdx.y;
  int p0 = blockIdx.x * 128;
  int t  = threadIdx.x;
  int h  = t >> 5;
  int pl = t & 31;

  float* ks = smem;
  float* vs = smem + LSEQ * 64;
  {
    const float4* ksrc = (const float4*)(kbuf + b * LSEQ * 64);
    const float4* vsrc = (const float4*)(vbuf + b * LSEQ * 64);
    float4* kd = (float4*)ks;
    float4* vd = (float4*)vs;
    for (int i = t; i < LSEQ * 16; i += 256) { kd[i] = ksrc[i]; vd[i] = vsrc[i]; }
  }

  // ---- Q phase: q[p][8h..8h+7] for p = p0 + pl + 32*i, i<4 (runs before the barrier) ----
  float qr[4][8];
  {
    const float4 b0 = *(const float4*)(bq + 8 * h);
    const float4 b1 = *(const float4*)(bq + 8 * h + 4);
    #pragma unroll
    for (int i = 0; i < 4; i++) {
      qr[i][0] = b0.x * QF; qr[i][1] = b0.y * QF; qr[i][2] = b0.z * QF; qr[i][3] = b0.w * QF;
      qr[i][4] = b1.x * QF; qr[i][5] = b1.y * QF; qr[i][6] = b1.z * QF; qr[i][7] = b1.w * QF;
    }
  }
  const float* zb = z + b * (CHN * HW) + p0 + pl;
  #pragma unroll 4
  for (int c = 0; c < 64; c++) {
    float4 w0 = *(const float4*)(wqT + c * 64 + 8 * h);
    float4 w1 = *(const float4*)(wqT + c * 64 + 8 * h + 4);
    float zv[4];
    #pragma unroll
    for (int i = 0; i < 4; i++) zv[i] = zb[c * HW + 32 * i];
    #pragma unroll
    for (int i = 0; i < 4; i++) {
      qr[i][0] = fmaf(zv[i], w0.x, qr[i][0]);
      qr[i][1] = fmaf(zv[i], w0.y, qr[i][1]);
      qr[i][2] = fmaf(zv[i], w0.z, qr[i][2]);
      qr[i][3] = fmaf(zv[i], w0.w, qr[i][3]);
      qr[i][4] = fmaf(zv[i], w1.x, qr[i][4]);
      qr[i][5] = fmaf(zv[i], w1.y, qr[i][5]);
      qr[i][6] = fmaf(zv[i], w1.z, qr[i][6]);
      qr[i][7] = fmaf(zv[i], w1.w, qr[i][7]);
    }
  }
  __syncthreads();

  // ---- Attention phase ----
  float acc[4][8];
  float li[4];
  #pragma unroll
  for (int i = 0; i < 4; i++) {
    li[i] = 0.f;
    #pragma unroll
    for (int d = 0; d < 8; d++) acc[i][d] = 0.f;
  }
  #pragma unroll 2
  for (int j = 0; j < LSEQ; j++) {
    float4 k0 = *(const float4*)(ks + j * 64 + 8 * h);
    float4 k1 = *(const float4*)(ks + j * 64 + 8 * h + 4);
    float4 v0 = *(const float4*)(vs + j * 64 + 8 * h);
    float4 v1 = *(const float4*)(vs + j * 64 + 8 * h + 4);
    #pragma unroll
    for (int i = 0; i < 4; i++) {
      float s = qr[i][0] * k0.x;
      s = fmaf(qr[i][1], k0.y, s);
      s = fmaf(qr[i][2], k0.z, s);
      s = fmaf(qr[i][3], k0.w, s);
      s = fmaf(qr[i][4], k1.x, s);
      s = fmaf(qr[i][5], k1.y, s);
      s = fmaf(qr[i][6], k1.z, s);
      s = fmaf(qr[i][7], k1.w, s);
      float e = __builtin_amdgcn_exp2f(s);
      li[i] += e;
      acc[i][0] = fmaf(e, v0.x, acc[i][0]);
      acc[i][1] = fmaf(e, v0.y, acc[i][1]);
      acc[i][2] = fmaf(e, v0.z, acc[i][2]);
      acc[i][3] = fmaf(e, v0.w, acc[i][3]);
      acc[i][4] = fmaf(e, v1.x, acc[i][4]);
      acc[i][5] = fmaf(e, v1.y, acc[i][5]);
      acc[i][6] = fmaf(e, v1.z, acc[i][6]);
      acc[i][7] = fmaf(e, v1.w, acc[i][7]);
    }
  }
  __syncthreads();   // all k/v reads done; smem reusable

  // ---- ao -> LDS, layout [128][65] (stride 65: 2 lanes/bank = free) ----
  float* ao = smem;
  #pragma unroll
  for (int i = 0; i < 4; i++) {
    float inv = 1.0f / li[i];
    int p = pl + 32 * i;
    #pragma unroll
    for (int d = 0; d < 8; d++) ao[p * 65 + 8 * h + d] = acc[i][d] * inv;
  }
  __syncthreads();

  // ---- O phase: out[p][co] = ao[p] . woT[:,co] + bo ----
  int q2 = t & 127;
  int chalf = __builtin_amdgcn_readfirstlane((t >> 7) & 1);  // wave-uniform -> scalar weight loads
  float acc2[32];
  #pragma unroll
  for (int j2 = 0; j2 < 32; j2++) acc2[j2] = bo[chalf * 32 + j2];
  const float* aor = ao + q2 * 65;
  #pragma unroll 4
  for (int c = 0; c < 64; c++) {
    float xv = aor[c];
    const float* wr = woT + c * 64 + chalf * 32;
    #pragma unroll
    for (int j2 = 0; j2 < 32; j2++) acc2[j2] = fmaf(xv, wr[j2], acc2[j2]);
  }
  float* ob = out + b * (CHN * HW) + p0 + q2;
  #pragma unroll
  for (int j2 = 0; j2 < 32; j2++) ob[(chalf * 32 + j2) * HW] = acc2[j2];
}

extern "C" void kernel_launch(void* const* d_in, const int* in_sizes, int n_in,
                              void* d_out, int out_size, void* d_ws, size_t ws_size,
                              hipStream_t stream) {
  const float* z    = (const float*)d_in[0];
  const float* cond = (const float*)d_in[1];
  const float* Wq = (const float*)d_in[2];  const float* bq = (const float*)d_in[3];
  const float* Aq = (const float*)d_in[4];  const float* Bq = (const float*)d_in[5];
  const float* Wk = (const float*)d_in[6];  const float* bk = (const float*)d_in[7];
  const float* Ak = (const float*)d_in[8];  const float* Bk = (const float*)d_in[9];
  const float* Wv = (const float*)d_in[10]; const float* bv = (const float*)d_in[11];
  const float* Av = (const float*)d_in[12]; const float* Bv = (const float*)d_in[13];
  const float* Wo = (const float*)d_in[14]; const float* bo = (const float*)d_in[15];
  const float* Ao = (const float*)d_in[16]; const float* Bo = (const float*)d_in[17];
  float* ws  = (float*)d_ws;
  float* out = (float*)d_out;

  prep_weights<<<416, 256, 0, stream>>>(Wq, Aq, Bq, Wk, Ak, Bk, Wv, Av, Bv, Wo, Ao, Bo, ws);
  kvproj<<<dim3(12, 2, 16), 128, 0, stream>>>(cond, ws + OFF_WK, ws + OFF_WV, ws + OFF_PA);
  kvreduce<<<616, 256, 0, stream>>>(ws + OFF_PA, bk, bv, ws + OFF_K, ws + OFF_V);
  megattn<<<dim3(32, 16), 256, 0, stream>>>(z, ws + OFF_WQ, bq, ws + OFF_K, ws + OFF_V,
                                            ws + OFF_WO, bo, out);
}